// Round 1
// baseline (6188.127 us; speedup 1.0000x reference)
//
#include <hip/hip_runtime.h>
#include <math.h>

#define B 64
#define S 32
#define NN 128
#define DV 512
#define DW 300
#define DH 1024
#define CLS 1024
#define T_CTRL 12
#define LL 4
#define NA 28
#define NE 16
#define MM 6

__device__ __forceinline__ float sigmoidf_(float x) { return 1.0f / (1.0f + expf(-x)); }

// ---------------- init state ----------------
__global__ void init_kernel(float* c_lstm, float* c_ctrl, float* att_stack, float* mem, float* stack_ptr) {
  int idx = blockIdx.x * 256 + threadIdx.x;   // 65536 threads
  if (idx < B * DH) { c_lstm[idx] = 0.f; c_ctrl[idx] = 0.f; }
  if (idx < B * NN * LL) att_stack[idx] = 0.f;
  if (idx < B * DV) mem[idx] = 0.f;
  if (idx < B * LL) stack_ptr[idx] = ((idx & (LL - 1)) == 0) ? 1.f : 0.f;
}

// ---------------- feat = attr_emb[v_idx] ----------------
__global__ void feat_gather_kernel(const int* __restrict__ v_idx, const float* __restrict__ attr_emb,
                                   float* __restrict__ feat) {
  int idx = blockIdx.x * 256 + threadIdx.x;   // over B*NN*(DV/4)
  int row = idx >> 7;                          // DV/4 = 128
  int kk = idx & 127;
  ((float4*)feat)[idx] = ((const float4*)attr_emb)[(size_t)v_idx[row] * 128 + kk];
}

// ---------------- LSTM step (fused GEMM + gates) ----------------
// grid = DH/4 blocks, 256 threads. Each block: 4 cols in each of the 4 gate sections, all 64 rows.
__global__ __launch_bounds__(256) void lstm_step_kernel(
    const int* __restrict__ questions, const float* __restrict__ enc_emb,
    const float* __restrict__ Wx, const float* __restrict__ Wh,
    const float* __restrict__ b_lstm,
    const float* __restrict__ h_in,   // nullptr for t==0 (h=0)
    float* __restrict__ h_out, float* __restrict__ c_st, int t)
{
  const int tid = threadIdx.x;
  const int j0 = blockIdx.x * 4;
  const int row = tid >> 2;   // 0..63
  const int col = tid & 3;    // 0..3
  __shared__ float As[64][36];
  __shared__ float Ws[32][4][4];   // [kk][col][gate]
  __shared__ int qid[64];
  if (tid < 64) qid[tid] = questions[tid * S + t];
  float ai = 0.f, af = 0.f, ag = 0.f, ao = 0.f;
  __syncthreads();

  // phase X: K = DW = 300
  for (int k0 = 0; k0 < DW; k0 += 32) {
    #pragma unroll
    for (int i = 0; i < 8; ++i) {
      int idx = tid + i * 256;
      int r = idx >> 5, kk = idx & 31, k = k0 + kk;
      As[r][kk] = (k < DW) ? enc_emb[qid[r] * DW + k] : 0.f;
    }
    {
      int idx = tid;
      #pragma unroll
      for (int i = 0; i < 2; ++i, idx += 256) {
        int kk = idx >> 4, cc = (idx >> 2) & 3, g = idx & 3, k = k0 + kk;
        Ws[kk][cc][g] = (k < DW) ? Wx[(size_t)k * (4 * DH) + g * DH + j0 + cc] : 0.f;
      }
    }
    __syncthreads();
    #pragma unroll
    for (int kk = 0; kk < 32; kk += 4) {
      float4 a  = *(const float4*)&As[row][kk];
      float4 w0 = *(const float4*)&Ws[kk + 0][col][0];
      float4 w1 = *(const float4*)&Ws[kk + 1][col][0];
      float4 w2 = *(const float4*)&Ws[kk + 2][col][0];
      float4 w3 = *(const float4*)&Ws[kk + 3][col][0];
      ai = fmaf(a.x, w0.x, ai); af = fmaf(a.x, w0.y, af); ag = fmaf(a.x, w0.z, ag); ao = fmaf(a.x, w0.w, ao);
      ai = fmaf(a.y, w1.x, ai); af = fmaf(a.y, w1.y, af); ag = fmaf(a.y, w1.z, ag); ao = fmaf(a.y, w1.w, ao);
      ai = fmaf(a.z, w2.x, ai); af = fmaf(a.z, w2.y, af); ag = fmaf(a.z, w2.z, ag); ao = fmaf(a.z, w2.w, ao);
      ai = fmaf(a.w, w3.x, ai); af = fmaf(a.w, w3.y, af); ag = fmaf(a.w, w3.z, ag); ao = fmaf(a.w, w3.w, ao);
    }
    __syncthreads();
  }

  // phase H: K = DH = 1024
  if (h_in != nullptr) {
    for (int k0 = 0; k0 < DH; k0 += 32) {
      #pragma unroll
      for (int i = 0; i < 8; ++i) {
        int idx = tid + i * 256;
        int r = idx >> 5, kk = idx & 31;
        As[r][kk] = h_in[r * DH + k0 + kk];
      }
      {
        int idx = tid;
        #pragma unroll
        for (int i = 0; i < 2; ++i, idx += 256) {
          int kk = idx >> 4, cc = (idx >> 2) & 3, g = idx & 3;
          Ws[kk][cc][g] = Wh[(size_t)(k0 + kk) * (4 * DH) + g * DH + j0 + cc];
        }
      }
      __syncthreads();
      #pragma unroll
      for (int kk = 0; kk < 32; kk += 4) {
        float4 a  = *(const float4*)&As[row][kk];
        float4 w0 = *(const float4*)&Ws[kk + 0][col][0];
        float4 w1 = *(const float4*)&Ws[kk + 1][col][0];
        float4 w2 = *(const float4*)&Ws[kk + 2][col][0];
        float4 w3 = *(const float4*)&Ws[kk + 3][col][0];
        ai = fmaf(a.x, w0.x, ai); af = fmaf(a.x, w0.y, af); ag = fmaf(a.x, w0.z, ag); ao = fmaf(a.x, w0.w, ao);
        ai = fmaf(a.y, w1.x, ai); af = fmaf(a.y, w1.y, af); ag = fmaf(a.y, w1.z, ag); ao = fmaf(a.y, w1.w, ao);
        ai = fmaf(a.z, w2.x, ai); af = fmaf(a.z, w2.y, af); ag = fmaf(a.z, w2.z, ag); ao = fmaf(a.z, w2.w, ao);
        ai = fmaf(a.w, w3.x, ai); af = fmaf(a.w, w3.y, af); ag = fmaf(a.w, w3.z, ag); ao = fmaf(a.w, w3.w, ao);
      }
      __syncthreads();
    }
  }

  int j = j0 + col;
  ai += b_lstm[j]; af += b_lstm[DH + j]; ag += b_lstm[2 * DH + j]; ao += b_lstm[3 * DH + j];
  float iv = sigmoidf_(ai), fv = sigmoidf_(af), gv = tanhf(ag), ov = sigmoidf_(ao);
  int idx = row * DH + j;
  float cn = fv * c_st[idx] + iv * gv;
  float hn = ov * tanhf(cn);
  c_st[idx] = cn;
  h_out[idx] = hn;
}

// ---------------- q_hidden gather ----------------
__global__ void qhid_gather_kernel(const float* __restrict__ outs, const int* __restrict__ qlen,
                                   float* __restrict__ q_hidden) {
  int b = blockIdx.x;
  int t = qlen[b] - 1;
  for (int k = threadIdx.x; k < DH; k += 256)
    q_hidden[b * DH + k] = outs[((size_t)t * B + b) * DH + k];
}

// ---------------- generic skinny GEMM: out(64 x COLS) = act([A0|A1](64 x K) @ W + bias) ----------------
// block = 256 threads computes a 16x16 tile. grid = cblocks * 4 (4 row tiles of 16).
// ACT: 0 none, 1 relu, 2 tanh. TRANSW: W indexed [j*ldw + k]. EPI==1: out = s04*memold + mp5*acc.
template<int ACT, bool TRANSW, int EPI>
__global__ __launch_bounds__(256) void gemm64_kernel(
    const float* __restrict__ A0, int K0, const float* __restrict__ A1, int K1,
    const float* __restrict__ W, int ldw, const float* __restrict__ bias,
    float* __restrict__ out, int COLS, int cblocks,
    const float* __restrict__ mp, const float* __restrict__ memold)
{
  const int tid = threadIdx.x;
  const int jb = blockIdx.x % cblocks;
  const int rb = blockIdx.x / cblocks;
  const int j0 = jb * 16;
  const int r0 = rb * 16;
  const int rg = tid & 15;
  const int cc = tid >> 4;
  const int K = K0 + K1;
  __shared__ float As[16][36];
  __shared__ float Wt[16][36];
  float acc = 0.f;
  for (int k0 = 0; k0 < K; k0 += 32) {
    {
      int idx = tid;
      #pragma unroll
      for (int i = 0; i < 2; ++i, idx += 256) {
        int r = idx >> 5, kk = idx & 31, k = k0 + kk;
        float v = 0.f;
        int rr = r0 + r;
        if (k < K0) v = A0[rr * K0 + k];
        else if (k < K) v = A1[rr * K1 + (k - K0)];
        As[r][kk] = v;
      }
    }
    {
      int idx = tid;
      #pragma unroll
      for (int i = 0; i < 2; ++i, idx += 256) {
        int kk, c;
        if (TRANSW) { c = idx >> 5; kk = idx & 31; }
        else        { kk = idx >> 4; c = idx & 15; }
        int k = k0 + kk, j = j0 + c;
        float v = 0.f;
        if (k < K && j < COLS)
          v = TRANSW ? W[(size_t)j * ldw + k] : W[(size_t)k * ldw + j];
        Wt[c][kk] = v;
      }
    }
    __syncthreads();
    #pragma unroll
    for (int kk = 0; kk < 32; kk += 4) {
      float4 a = *(const float4*)&As[rg][kk];
      float4 w = *(const float4*)&Wt[cc][kk];
      acc = fmaf(a.x, w.x, acc);
      acc = fmaf(a.y, w.y, acc);
      acc = fmaf(a.z, w.z, acc);
      acc = fmaf(a.w, w.w, acc);
    }
    __syncthreads();
  }
  int j = j0 + cc, r = r0 + rg;
  if (j < COLS) {
    float v;
    if (EPI == 1) {
      const float* m = &mp[r * MM];
      float s04 = m[0] + m[1] + m[2] + m[3] + m[4];
      v = s04 * memold[r * COLS + j] + m[5] * acc;
    } else {
      v = acc + (bias ? bias[j] : 0.f);
      if (ACT == 1) v = fmaxf(v, 0.f);
      else if (ACT == 2) v = tanhf(v);
    }
    out[r * COLS + j] = v;
  }
}

// ---------------- module_prob = softmax(cq @ W_mod) ----------------
__global__ void mod_prob_kernel(const float* __restrict__ cq, const float* __restrict__ W_mod,
                                float* __restrict__ module_prob) {
  int b = blockIdx.x, lane = threadIdx.x;   // 64 threads
  float acc[MM] = {0.f, 0.f, 0.f, 0.f, 0.f, 0.f};
  for (int k = lane; k < DH; k += 64) {
    float a = cq[b * DH + k];
    const float* wr = &W_mod[k * MM];
    #pragma unroll
    for (int m = 0; m < MM; ++m) acc[m] = fmaf(a, wr[m], acc[m]);
  }
  #pragma unroll
  for (int m = 0; m < MM; ++m)
    for (int off = 32; off > 0; off >>= 1) acc[m] += __shfl_xor(acc[m], off);
  if (lane == 0) {
    float mx = acc[0];
    #pragma unroll
    for (int m = 1; m < MM; ++m) mx = fmaxf(mx, acc[m]);
    float e[MM], sm = 0.f;
    #pragma unroll
    for (int m = 0; m < MM; ++m) { e[m] = expf(acc[m] - mx); sm += e[m]; }
    #pragma unroll
    for (int m = 0; m < MM; ++m) module_prob[b * MM + m] = e[m] / sm;
  }
}

// ---------------- we = softmax(c_i @ edge^T) ----------------
__global__ void we_kernel(const float* __restrict__ c_i, const float* __restrict__ edge,
                          float* __restrict__ we) {
  int b = blockIdx.x, lane = threadIdx.x;   // 64 threads
  float acc[NE];
  #pragma unroll
  for (int e = 0; e < NE; ++e) acc[e] = 0.f;
  for (int k = lane; k < DV; k += 64) {
    float a = c_i[b * DV + k];
    #pragma unroll
    for (int e = 0; e < NE; ++e) acc[e] = fmaf(a, edge[e * DV + k], acc[e]);
  }
  #pragma unroll
  for (int e = 0; e < NE; ++e)
    for (int off = 32; off > 0; off >>= 1) acc[e] += __shfl_xor(acc[e], off);
  if (lane == 0) {
    float mx = acc[0];
    #pragma unroll
    for (int e = 1; e < NE; ++e) mx = fmaxf(mx, acc[e]);
    float ex[NE], sm = 0.f;
    #pragma unroll
    for (int e = 0; e < NE; ++e) { ex[e] = expf(acc[e] - mx); sm += ex[e]; }
    #pragma unroll
    for (int e = 0; e < NE; ++e) we[b * NE + e] = ex[e] / sm;
  }
}

// ---------------- attention: al -> masked softmax -> c_ctrl ----------------
__global__ __launch_bounds__(256) void attention_kernel(
    const float* __restrict__ outs, const float* __restrict__ attW,
    const int* __restrict__ qlen, float* __restrict__ c_ctrl) {
  int b = blockIdx.x, tid = threadIdx.x;
  int wave = tid >> 6, lane = tid & 63;
  __shared__ float aw[DH];
  __shared__ float al[S];
  __shared__ float cvs[S];
  for (int k = tid; k < DH; k += 256) aw[k] = attW[b * DH + k];
  __syncthreads();
  for (int s = wave * 8; s < wave * 8 + 8; ++s) {
    const float* orow = &outs[((size_t)s * B + b) * DH];
    float p = 0.f;
    for (int k = lane; k < DH; k += 64) p = fmaf(orow[k], aw[k], p);
    #pragma unroll
    for (int off = 32; off > 0; off >>= 1) p += __shfl_xor(p, off);
    if (lane == 0) al[s] = p;
  }
  __syncthreads();
  if (tid < 64) {
    int len = qlen[b];
    float v = (tid < S && tid < len) ? al[tid] : -1e9f;
    float mx = v;
    #pragma unroll
    for (int off = 32; off > 0; off >>= 1) mx = fmaxf(mx, __shfl_xor(mx, off));
    float e = expf(v - mx);
    float sm = e;
    #pragma unroll
    for (int off = 32; off > 0; off >>= 1) sm += __shfl_xor(sm, off);
    if (tid < S) cvs[tid] = e / sm;
  }
  __syncthreads();
  for (int h = tid; h < DH; h += 256) {
    float a = 0.f;
    #pragma unroll 4
    for (int s = 0; s < S; ++s) a = fmaf(cvs[s], outs[((size_t)s * B + b) * DH + h], a);
    c_ctrl[b * DH + h] = a;
  }
}

// ---------------- stack machine: one block per batch element ----------------
__global__ __launch_bounds__(256) void stack_kernel(
    const float* __restrict__ feat, const float* __restrict__ u,
    const float* __restrict__ module_prob, const float* __restrict__ we,
    const int* __restrict__ cat_mat, const float* __restrict__ conn,
    float* __restrict__ att_stack, float* __restrict__ stack_ptr,
    float* __restrict__ mp_out, float* __restrict__ pooled)
{
  int b = blockIdx.x, tid = threadIdx.x;
  int wave = tid >> 6, lane = tid & 63;
  __shared__ float sptr[LL], spfw[LL], spbw[LL], smp[MM];
  __shared__ float a_in[NN], a_find[NN], a_trans[NN], a_prev[NN], a_w4[NN];
  __shared__ float we_s[NE];
  __shared__ float s_asum;
  if (tid < NE) we_s[tid] = we[b * NE + tid];
  if (tid == 0) {
    float p0 = stack_ptr[b * LL + 0], p1 = stack_ptr[b * LL + 1];
    float p2 = stack_ptr[b * LL + 2], p3 = stack_ptr[b * LL + 3];
    sptr[0] = p0; sptr[1] = p1; sptr[2] = p2; sptr[3] = p3;
    spfw[0] = 0.f;      spfw[1] = p0; spfw[2] = p1; spfw[3] = p2 + p3;
    spbw[0] = p0 + p1;  spbw[1] = p2; spbw[2] = p3; spbw[3] = 0.f;
    float val[MM];
    val[0] = rintf(p0 + p1 + p2 + p3);
    val[1] = rintf(p0 + p1 + p2);
    val[2] = rintf(p1 + p2 + p3);
    val[3] = val[2];
    val[4] = rintf(p2 + p3);
    val[5] = val[2];
    float mpv[MM], ssum = 0.f;
    #pragma unroll
    for (int m = 0; m < MM; ++m) { mpv[m] = module_prob[b * MM + m] * val[m]; ssum += mpv[m]; }
    float inv = (ssum > 0.f) ? 1.f / ssum : 1.f;
    #pragma unroll
    for (int m = 0; m < MM; ++m) { smp[m] = mpv[m] * inv; mp_out[b * MM + m] = smp[m]; }
  }
  __syncthreads();
  // a_in, a_prev
  if (tid < NN) {
    float4 st = *(const float4*)&att_stack[(b * NN + tid) * LL];
    a_in[tid]   = st.x * sptr[0] + st.y * sptr[1] + st.z * sptr[2] + st.w * sptr[3];
    a_prev[tid] = st.x * spbw[0] + st.y * spbw[1] + st.z * spbw[2] + st.w * spbw[3];
  }
  __syncthreads();
  // a_find: wave-per-n reduction over DV
  for (int n = wave; n < NN; n += 4) {
    const float4* fp = (const float4*)&feat[((size_t)b * NN + n) * DV];
    const float4* up = (const float4*)&u[b * DV];
    float p = 0.f;
    for (int k = lane; k < DV / 4; k += 64) {
      float4 f = fp[k]; float4 uu = up[k];
      p += f.x * uu.x + f.y * uu.y + f.z * uu.z + f.w * uu.w;
    }
    #pragma unroll
    for (int off = 32; off > 0; off >>= 1) p += __shfl_xor(p, off);
    if (lane == 0) a_find[n] = sigmoidf_(p * 0.04419417382415922f);  // 1/sqrt(512)
  }
  __syncthreads();
  // a_trans, a_w4, asum
  if (tid < NN) {
    const int* crow = &cat_mat[((size_t)b * NN + tid) * NN];
    const float* nrow = &conn[((size_t)b * NN + tid) * NN];
    float acc = 0.f;
    #pragma unroll 4
    for (int jj = 0; jj < NN; ++jj)
      acc = fmaf(we_s[crow[jj]] * nrow[jj], a_in[jj], acc);
    a_trans[tid] = fminf(acc, 1.f);
    a_w4[tid] = fminf(a_prev[tid], a_in[tid]);
  }
  if (tid == 255) {
    float s = 0.f;
    for (int n = 0; n < NN; ++n) s += a_in[n];
    s_asum = s + 1e-6f;
  }
  __syncthreads();
  // pooled
  for (int d = tid; d < DV; d += 256) {
    float acc = 0.f;
    for (int n = 0; n < NN; ++n) acc = fmaf(a_in[n], feat[((size_t)b * NN + n) * DV + d], acc);
    pooled[b * DV + d] = acc / s_asum;
  }
  // att_stack update (in place) + stack_ptr
  #pragma unroll
  for (int i = 0; i < 2; ++i) {
    int e = tid + i * 256;   // 512 elements
    int n = e >> 2, l = e & 3;
    float st = att_stack[(b * NN + n) * LL + l];
    float keep = smp[0] + smp[5] + smp[1] * (1.f - spfw[l]) + (smp[2] + smp[3]) * (1.f - sptr[l])
               + smp[4] * (1.f - spbw[l]);
    float add = spfw[l] * smp[1] * a_find[n]
              + sptr[l] * (smp[2] * a_trans[n] + smp[3] * a_in[n] * a_find[n])
              + spbw[l] * smp[4] * a_w4[n];
    att_stack[(b * NN + n) * LL + l] = keep * st + add;
  }
  if (tid < LL) {
    int l = tid;
    stack_ptr[b * LL + l] = (smp[0] + smp[2] + smp[3]) * sptr[l] + smp[1] * spfw[l]
                          + (smp[4] + smp[5]) * spbw[l];
  }
}

extern "C" void kernel_launch(void* const* d_in, const int* in_sizes, int n_in,
                              void* d_out, int out_size, void* d_ws, size_t ws_size,
                              hipStream_t stream) {
  const int*   questions = (const int*)d_in[0];
  const int*   qlen      = (const int*)d_in[1];
  const float* conn      = (const float*)d_in[2];
  const int*   cat_mat   = (const int*)d_in[3];
  const int*   v_idx     = (const int*)d_in[4];
  const float* attr_emb  = (const float*)d_in[5];
  const float* edge_cat  = (const float*)d_in[6];
  const float* enc_emb   = (const float*)d_in[7];
  const float* Wx        = (const float*)d_in[8];
  const float* Wh        = (const float*)d_in[9];
  const float* b_lstm    = (const float*)d_in[10];
  const float* W_cq      = (const float*)d_in[11];
  const float* b_cq      = (const float*)d_in[12];
  const float* W_mod     = (const float*)d_in[13];
  const float* W_att     = (const float*)d_in[14];
  const float* W_q       = (const float*)d_in[15];
  const float* b_q       = (const float*)d_in[16];
  const float* W_find    = (const float*)d_in[17];
  const float* W_desc    = (const float*)d_in[18];
  const float* W_cls1    = (const float*)d_in[19];
  const float* b_cls1    = (const float*)d_in[20];
  const float* W_cls2    = (const float*)d_in[21];
  const float* b_cls2    = (const float*)d_in[22];
  float* logits = (float*)d_out;

  float* w = (float*)d_ws;
  size_t off = 0;
  float* feat      = w + off; off += (size_t)B * NN * DV;   // 4,194,304
  float* outs      = w + off; off += (size_t)S * B * DH;    // 2,097,152
  float* cq        = w + off; off += B * DH;
  float* attW      = w + off; off += B * DH;
  float* c_ctrl    = w + off; off += B * DH;
  float* q_hidden  = w + off; off += B * DH;
  float* c_lstm    = w + off; off += B * DH;
  float* c_i       = w + off; off += B * DV;
  float* u_buf     = w + off; off += B * DV;
  float* mprob     = w + off; off += B * MM;
  float* we_buf    = w + off; off += B * NE;
  float* att_stack = w + off; off += B * NN * LL;
  float* stack_ptr = w + off; off += B * LL;
  float* mem       = w + off; off += B * DV;
  float* pooled    = w + off; off += B * DV;
  float* mp_buf    = w + off; off += B * MM;
  float* h1        = w + off; off += B * CLS;

  init_kernel<<<256, 256, 0, stream>>>(c_lstm, c_ctrl, att_stack, mem, stack_ptr);
  feat_gather_kernel<<<(B * NN * (DV / 4)) / 256, 256, 0, stream>>>(v_idx, attr_emb, feat);

  for (int t = 0; t < S; ++t) {
    const float* hin = (t == 0) ? nullptr : outs + (size_t)(t - 1) * B * DH;
    lstm_step_kernel<<<DH / 4, 256, 0, stream>>>(questions, enc_emb, Wx, Wh, b_lstm,
                                                 hin, outs + (size_t)t * B * DH, c_lstm, t);
  }
  qhid_gather_kernel<<<B, 256, 0, stream>>>(outs, qlen, q_hidden);

  for (int it = 0; it < T_CTRL; ++it) {
    // cq = tanh([c_ctrl | q_hidden] @ W_cq + b_cq)
    gemm64_kernel<2, false, 0><<<(DH / 16) * 4, 256, 0, stream>>>(
        c_ctrl, DH, q_hidden, DH, W_cq, DH, b_cq, cq, DH, DH / 16, nullptr, nullptr);
    // module_prob = softmax(cq @ W_mod)
    mod_prob_kernel<<<B, 64, 0, stream>>>(cq, W_mod, mprob);
    // attW = cq @ W_att
    gemm64_kernel<0, false, 0><<<(DH / 16) * 4, 256, 0, stream>>>(
        cq, DH, nullptr, 0, W_att, DH, nullptr, attW, DH, DH / 16, nullptr, nullptr);
    // attention -> c_ctrl
    attention_kernel<<<B, 256, 0, stream>>>(outs, attW, qlen, c_ctrl);
    // c_i = relu(c_ctrl @ W_q + b_q)
    gemm64_kernel<1, false, 0><<<(DV / 16) * 4, 256, 0, stream>>>(
        c_ctrl, DH, nullptr, 0, W_q, DV, b_q, c_i, DV, DV / 16, nullptr, nullptr);
    // u = c_i @ W_find^T
    gemm64_kernel<0, true, 0><<<(DV / 16) * 4, 256, 0, stream>>>(
        c_i, DV, nullptr, 0, W_find, DV, nullptr, u_buf, DV, DV / 16, nullptr, nullptr);
    // we = softmax(c_i @ edge^T)
    we_kernel<<<B, 64, 0, stream>>>(c_i, edge_cat, we_buf);
    // stack machine: a_find/a_in/a_trans/a_prev/pooled + in-place stack/ptr update, mp out
    stack_kernel<<<B, 256, 0, stream>>>(feat, u_buf, mprob, we_buf, cat_mat, conn,
                                        att_stack, stack_ptr, mp_buf, pooled);
    // mem = s04*mem + mp5*(pooled @ W_desc)
    gemm64_kernel<0, false, 1><<<(DV / 16) * 4, 256, 0, stream>>>(
        pooled, DV, nullptr, 0, W_desc, DV, nullptr, mem, DV, DV / 16, mp_buf, mem);
  }

  // classifier
  gemm64_kernel<1, false, 0><<<(CLS / 16) * 4, 256, 0, stream>>>(
      mem, DV, q_hidden, DH, W_cls1, CLS, b_cls1, h1, CLS, CLS / 16, nullptr, nullptr);
  gemm64_kernel<0, false, 0><<<2 * 4, 256, 0, stream>>>(
      h1, CLS, nullptr, 0, W_cls2, NA, b_cls2, logits, NA, 2, nullptr, nullptr);
}

// Round 2
// 3196.676 us; speedup vs baseline: 1.9358x; 1.9358x over previous
//
#include <hip/hip_runtime.h>
#include <math.h>

#define B 64
#define S 32
#define NN 128
#define DV 512
#define DW 300
#define DH 1024
#define CLS 1024
#define T_CTRL 12
#define LL 4
#define NA 28
#define NE 16
#define MM 6

__device__ __forceinline__ float sigmoidf_(float x) { return 1.0f / (1.0f + expf(-x)); }

// ---------------- init state ----------------
__global__ void init_kernel(float* c_lstm, float* c_ctrl, float* att_stack, float* mem, float* stack_ptr) {
  int idx = blockIdx.x * 256 + threadIdx.x;
  if (idx < B * DH) { c_lstm[idx] = 0.f; c_ctrl[idx] = 0.f; }
  if (idx < B * NN * LL) att_stack[idx] = 0.f;
  if (idx < B * DV) mem[idx] = 0.f;
  if (idx < B * LL) stack_ptr[idx] = ((idx & (LL - 1)) == 0) ? 1.f : 0.f;
}

// ---------------- embq: gathered question embeddings, rows t*B+b, padded K 300->320 ----------------
__global__ void embq_kernel(const int* __restrict__ questions, const float* __restrict__ enc_emb,
                            float* __restrict__ embq) {
  int row = blockIdx.x;            // 0..S*B-1,  t = row/64, b = row%64
  int t = row >> 6, b = row & 63;
  int qid = questions[b * S + t];
  int c = threadIdx.x;             // 320 threads
  embq[(size_t)row * 320 + c] = (c < DW) ? enc_emb[(size_t)qid * DW + c] : 0.f;
}

// ---------------- split-K partial GEMM ----------------
// out rows M=64. Block: 256 threads, tile 64 rows x 64 cols, thread = 4r x 4c.
// grid.x = col tiles (64 cols), grid.y = SK chunks (Kc each, mult of 32).
// A = [A0 (AK0 cols) | A1 (K-AK0 cols)], rows 64.
// W rows: k < WK0 -> W0 (zero row if k >= Kw0), else W1 at k-WK0.
// W cols (W0 region): j < Ca -> W0, else W0b at j-Ca. TRANSW: W[j][k] indexing.
struct GemmP {
  const float* A0; const float* A1; int AK0;
  const float* W0; int ld0;
  const float* W0b; int ld0b; int Ca;
  const float* W1; int ld1; int WK0; int Kw0;
  float* out; int C; int Cld; int K; int Kc;
};

template<bool TRANSW>
__global__ __launch_bounds__(256) void gemm_part(GemmP g) {
  __shared__ float Ast[32][65];   // [k][row], pad 65 -> 2-way free column reads
  __shared__ float Ws[32][64];    // [k][col], rows 256B aligned for b128 broadcast
  const int tid = threadIdx.x;
  const int j0 = blockIdx.x * 64;
  const int kbeg = blockIdx.y * g.Kc;
  const int kend = (kbeg + g.Kc < g.K) ? kbeg + g.Kc : g.K;
  const int rg = tid & 15, cg = tid >> 4;
  float acc[4][4] = {};

  for (int kt = kbeg; kt < kend; kt += 32) {
    // stage A (transposed): 64 rows x 32 k
    #pragma unroll
    for (int it = 0; it < 2; ++it) {
      int idx = tid + it * 256;
      int r = idx >> 3, k4 = (idx & 7) * 4;
      int k = kt + k4;
      float4 av;
      if (k < g.AK0) av = *(const float4*)&g.A0[(size_t)r * g.AK0 + k];
      else           av = *(const float4*)&g.A1[(size_t)r * (g.K - g.AK0) + (k - g.AK0)];
      Ast[k4 + 0][r] = av.x; Ast[k4 + 1][r] = av.y; Ast[k4 + 2][r] = av.z; Ast[k4 + 3][r] = av.w;
    }
    // stage W: 32 k x 64 cols
    if (!TRANSW) {
      #pragma unroll
      for (int it = 0; it < 2; ++it) {
        int idx = tid + it * 256;
        int kk = kt + (idx >> 4);
        int j4 = (idx & 15) * 4;
        const float* wrow = nullptr;
        int kw = kk;
        if (kk < g.WK0) { if (kk < g.Kw0) wrow = g.W0 + (size_t)kk * g.ld0; }
        else { wrow = g.W1 + (size_t)(kk - g.WK0) * g.ld1; }
        float v[4];
        #pragma unroll
        for (int m = 0; m < 4; ++m) {
          int j = j0 + j4 + m;
          float x = 0.f;
          if (j < g.C) {
            if (j < g.Ca) { if (wrow) x = wrow[j]; }
            else { if (kk < g.Kw0) x = g.W0b[(size_t)kk * g.ld0b + (j - g.Ca)]; }
          }
          v[m] = x;
        }
        *(float4*)&Ws[idx >> 4][j4] = make_float4(v[0], v[1], v[2], v[3]);
      }
    } else {
      #pragma unroll
      for (int it = 0; it < 2; ++it) {
        int idx = tid + it * 256;
        int jloc = idx >> 3, k4 = (idx & 7) * 4;
        int j = j0 + jloc;
        float4 wv = make_float4(0.f, 0.f, 0.f, 0.f);
        if (j < g.C) {
          const float* wr = (j < g.Ca) ? g.W0 + (size_t)j * g.ld0
                                       : g.W0b + (size_t)(j - g.Ca) * g.ld0b;
          wv = *(const float4*)&wr[kt + k4];
        }
        Ws[k4 + 0][jloc] = wv.x; Ws[k4 + 1][jloc] = wv.y; Ws[k4 + 2][jloc] = wv.z; Ws[k4 + 3][jloc] = wv.w;
      }
    }
    __syncthreads();
    #pragma unroll
    for (int k = 0; k < 32; ++k) {
      float a0 = Ast[k][rg], a1 = Ast[k][rg + 16], a2 = Ast[k][rg + 32], a3 = Ast[k][rg + 48];
      float4 w = *(const float4*)&Ws[k][cg * 4];
      acc[0][0] = fmaf(a0, w.x, acc[0][0]); acc[0][1] = fmaf(a0, w.y, acc[0][1]);
      acc[0][2] = fmaf(a0, w.z, acc[0][2]); acc[0][3] = fmaf(a0, w.w, acc[0][3]);
      acc[1][0] = fmaf(a1, w.x, acc[1][0]); acc[1][1] = fmaf(a1, w.y, acc[1][1]);
      acc[1][2] = fmaf(a1, w.z, acc[1][2]); acc[1][3] = fmaf(a1, w.w, acc[1][3]);
      acc[2][0] = fmaf(a2, w.x, acc[2][0]); acc[2][1] = fmaf(a2, w.y, acc[2][1]);
      acc[2][2] = fmaf(a2, w.z, acc[2][2]); acc[2][3] = fmaf(a2, w.w, acc[2][3]);
      acc[3][0] = fmaf(a3, w.x, acc[3][0]); acc[3][1] = fmaf(a3, w.y, acc[3][1]);
      acc[3][2] = fmaf(a3, w.z, acc[3][2]); acc[3][3] = fmaf(a3, w.w, acc[3][3]);
    }
    __syncthreads();
  }
  float* op = g.out + (size_t)blockIdx.y * 64 * g.Cld;
  int j = j0 + cg * 4;
  if (j < g.Cld) {
    #pragma unroll
    for (int m = 0; m < 4; ++m)
      *(float4*)&op[(size_t)(rg + 16 * m) * g.Cld + j] = make_float4(acc[m][0], acc[m][1], acc[m][2], acc[m][3]);
  }
}

// ---------------- split-K reduce + epilogue. ACT: 0 none, 1 relu, 2 tanh. EPI 1: mem update ----------------
template<int ACT, int EPI>
__global__ __launch_bounds__(256) void reduce_k(const float* __restrict__ part, int SK, int Cld, int total4,
                                                const float* __restrict__ bias, float* __restrict__ out,
                                                const float* __restrict__ mp) {
  int idx = blockIdx.x * 256 + threadIdx.x;
  if (idx >= total4) return;
  size_t stride4 = (size_t)16 * Cld;   // 64*Cld/4
  const float4* p4 = (const float4*)part;
  float4 s = p4[idx];
  for (int k = 1; k < SK; ++k) {
    float4 p = p4[(size_t)k * stride4 + idx];
    s.x += p.x; s.y += p.y; s.z += p.z; s.w += p.w;
  }
  if (EPI == 1) {
    int r = idx / (Cld / 4);
    const float* m = mp + r * MM;
    float s04 = m[0] + m[1] + m[2] + m[3] + m[4];
    float4 o = ((float4*)out)[idx];
    s.x = s04 * o.x + m[5] * s.x; s.y = s04 * o.y + m[5] * s.y;
    s.z = s04 * o.z + m[5] * s.z; s.w = s04 * o.w + m[5] * s.w;
  } else {
    if (bias) {
      int j = (idx * 4) % Cld;
      float4 bb = *(const float4*)&bias[j];
      s.x += bb.x; s.y += bb.y; s.z += bb.z; s.w += bb.w;
    }
    if (ACT == 1) { s.x = fmaxf(s.x, 0.f); s.y = fmaxf(s.y, 0.f); s.z = fmaxf(s.z, 0.f); s.w = fmaxf(s.w, 0.f); }
    else if (ACT == 2) { s.x = tanhf(s.x); s.y = tanhf(s.y); s.z = tanhf(s.z); s.w = tanhf(s.w); }
  }
  ((float4*)out)[idx] = s;
}

// ---------------- LSTM gate epilogue: reduce partials + gates ----------------
__global__ __launch_bounds__(256) void lstm_gate_kernel(const float* __restrict__ part, int SK,
                                                        const float* __restrict__ b_lstm,
                                                        float* __restrict__ h_out, float* __restrict__ c_st) {
  int idx = blockIdx.x * 256 + threadIdx.x;   // B*DH
  int b = idx >> 10, j = idx & 1023;
  const float* pb = part + (size_t)b * 4096;
  float gi = 0.f, gf = 0.f, gg = 0.f, go = 0.f;
  for (int k = 0; k < SK; ++k) {
    const float* p = pb + (size_t)k * 64 * 4096;
    gi += p[j]; gf += p[1024 + j]; gg += p[2048 + j]; go += p[3072 + j];
  }
  gi += b_lstm[j]; gf += b_lstm[1024 + j]; gg += b_lstm[2048 + j]; go += b_lstm[3072 + j];
  float c = sigmoidf_(gf) * c_st[idx] + sigmoidf_(gi) * tanhf(gg);
  h_out[idx] = sigmoidf_(go) * tanhf(c);
  c_st[idx] = c;
}

// ---------------- q_hidden gather ----------------
__global__ void qhid_gather_kernel(const float* __restrict__ outs, const int* __restrict__ qlen,
                                   float* __restrict__ q_hidden) {
  int b = blockIdx.x;
  int t = qlen[b] - 1;
  for (int k = threadIdx.x; k < DH; k += 256)
    q_hidden[b * DH + k] = outs[((size_t)t * B + b) * DH + k];
}

// ---------------- attention: al -> masked softmax -> c_ctrl ----------------
__global__ __launch_bounds__(256) void attention_kernel(
    const float* __restrict__ outs, const float* __restrict__ attW, int aw_stride,
    const int* __restrict__ qlen, float* __restrict__ c_ctrl) {
  int b = blockIdx.x, tid = threadIdx.x;
  int wave = tid >> 6, lane = tid & 63;
  __shared__ float aw[DH];
  __shared__ float al[S];
  __shared__ float cvs[S];
  for (int k = tid; k < DH; k += 256) aw[k] = attW[(size_t)b * aw_stride + k];
  __syncthreads();
  for (int s = wave * 8; s < wave * 8 + 8; ++s) {
    const float* orow = &outs[((size_t)s * B + b) * DH];
    float p = 0.f;
    for (int k = lane; k < DH; k += 64) p = fmaf(orow[k], aw[k], p);
    #pragma unroll
    for (int off = 32; off > 0; off >>= 1) p += __shfl_xor(p, off);
    if (lane == 0) al[s] = p;
  }
  __syncthreads();
  if (tid < 64) {
    int len = qlen[b];
    float v = (tid < S && tid < len) ? al[tid] : -1e9f;
    float mx = v;
    #pragma unroll
    for (int off = 32; off > 0; off >>= 1) mx = fmaxf(mx, __shfl_xor(mx, off));
    float e = expf(v - mx);
    float sm = e;
    #pragma unroll
    for (int off = 32; off > 0; off >>= 1) sm += __shfl_xor(sm, off);
    if (tid < S) cvs[tid] = e / sm;
  }
  __syncthreads();
  for (int h = tid; h < DH; h += 256) {
    float a = 0.f;
    #pragma unroll 4
    for (int s = 0; s < S; ++s) a = fmaf(cvs[s], outs[((size_t)s * B + b) * DH + h], a);
    c_ctrl[b * DH + h] = a;
  }
}

// ---------------- stack machine (on-the-fly feat gather, fused mod/we softmax) ----------------
__global__ __launch_bounds__(256) void stack_kernel(
    const int* __restrict__ v_idx, const float* __restrict__ attr_emb,
    const float* __restrict__ uwe,  // [64][528]: u=0..511, we logits=512..527
    const float* __restrict__ am,   // [64][1032]: attW 0..1023, mod logits 1024..1029
    const int* __restrict__ cat_mat, const float* __restrict__ conn,
    const float* __restrict__ stack_ptr_in,
    float* __restrict__ att_stack, float* __restrict__ stack_ptr,
    float* __restrict__ mp_out, float* __restrict__ pooled)
{
  int b = blockIdx.x, tid = threadIdx.x;
  int wave = tid >> 6, lane = tid & 63;
  __shared__ float sptr[LL], spfw[LL], spbw[LL], smp[MM], we_s[NE];
  __shared__ float a_in[NN], a_find[NN], a_trans[NN], a_w4[NN];
  __shared__ int vid[NN];
  __shared__ float s_asum;
  if (tid < NN) vid[tid] = v_idx[b * NN + tid];
  if (tid == 0) {
    // we = softmax over 16 logits
    const float* wl = &uwe[(size_t)b * 528 + 512];
    float mx = wl[0];
    for (int e = 1; e < NE; ++e) mx = fmaxf(mx, wl[e]);
    float sm = 0.f;
    for (int e = 0; e < NE; ++e) { we_s[e] = expf(wl[e] - mx); sm += we_s[e]; }
    for (int e = 0; e < NE; ++e) we_s[e] /= sm;
    // module_prob = softmax over 6 logits
    const float* ml = &am[(size_t)b * 1032 + 1024];
    float mx2 = ml[0];
    for (int m = 1; m < MM; ++m) mx2 = fmaxf(mx2, ml[m]);
    float e6[MM], sm2 = 0.f;
    for (int m = 0; m < MM; ++m) { e6[m] = expf(ml[m] - mx2); sm2 += e6[m]; }
    float p0 = stack_ptr_in[b * LL + 0], p1 = stack_ptr_in[b * LL + 1];
    float p2 = stack_ptr_in[b * LL + 2], p3 = stack_ptr_in[b * LL + 3];
    sptr[0] = p0; sptr[1] = p1; sptr[2] = p2; sptr[3] = p3;
    spfw[0] = 0.f;     spfw[1] = p0; spfw[2] = p1; spfw[3] = p2 + p3;
    spbw[0] = p0 + p1; spbw[1] = p2; spbw[2] = p3; spbw[3] = 0.f;
    float val[MM];
    val[0] = rintf(p0 + p1 + p2 + p3);
    val[1] = rintf(p0 + p1 + p2);
    val[2] = rintf(p1 + p2 + p3);
    val[3] = val[2];
    val[4] = rintf(p2 + p3);
    val[5] = val[2];
    float mpv[MM], ssum = 0.f;
    #pragma unroll
    for (int m = 0; m < MM; ++m) { mpv[m] = (e6[m] / sm2) * val[m]; ssum += mpv[m]; }
    float inv = (ssum > 0.f) ? 1.f / ssum : 1.f;
    #pragma unroll
    for (int m = 0; m < MM; ++m) { smp[m] = mpv[m] * inv; mp_out[b * MM + m] = smp[m]; }
  }
  __syncthreads();
  if (tid < NN) {
    float4 st = *(const float4*)&att_stack[(b * NN + tid) * LL];
    a_in[tid] = st.x * sptr[0] + st.y * sptr[1] + st.z * sptr[2] + st.w * sptr[3];
    float ap  = st.x * spbw[0] + st.y * spbw[1] + st.z * spbw[2] + st.w * spbw[3];
    a_w4[tid] = ap;   // temp: a_prev
  }
  __syncthreads();
  // a_find: wave-per-n dot(attr_emb[vid[n]], u)
  const float4* up = (const float4*)&uwe[(size_t)b * 528];
  for (int n = wave; n < NN; n += 4) {
    const float4* fp = (const float4*)&attr_emb[(size_t)vid[n] * DV];
    float p = 0.f;
    for (int k = lane; k < DV / 4; k += 64) {
      float4 f = fp[k]; float4 uu = up[k];
      p += f.x * uu.x + f.y * uu.y + f.z * uu.z + f.w * uu.w;
    }
    #pragma unroll
    for (int off = 32; off > 0; off >>= 1) p += __shfl_xor(p, off);
    if (lane == 0) a_find[n] = sigmoidf_(p * 0.04419417382415922f);  // 1/sqrt(512)
  }
  __syncthreads();
  if (tid < NN) {
    const int* crow = &cat_mat[((size_t)b * NN + tid) * NN];
    const float* nrow = &conn[((size_t)b * NN + tid) * NN];
    float acc = 0.f;
    #pragma unroll 4
    for (int jj = 0; jj < NN; ++jj)
      acc = fmaf(we_s[crow[jj]] * nrow[jj], a_in[jj], acc);
    a_trans[tid] = fminf(acc, 1.f);
    a_w4[tid] = fminf(a_w4[tid], a_in[tid]);   // min(a_prev, a_in)
  }
  if (tid == 255) {
    float s = 0.f;
    for (int n = 0; n < NN; ++n) s += a_in[n];
    s_asum = s + 1e-6f;
  }
  __syncthreads();
  // pooled (uses old a_in)
  for (int d = tid; d < DV; d += 256) {
    float acc = 0.f;
    for (int n = 0; n < NN; ++n) acc = fmaf(a_in[n], attr_emb[(size_t)vid[n] * DV + d], acc);
    pooled[b * DV + d] = acc / s_asum;
  }
  // att_stack in-place update + stack_ptr
  #pragma unroll
  for (int i = 0; i < 2; ++i) {
    int e = tid + i * 256;
    int n = e >> 2, l = e & 3;
    float st = att_stack[(b * NN + n) * LL + l];
    float keep = smp[0] + smp[5] + smp[1] * (1.f - spfw[l]) + (smp[2] + smp[3]) * (1.f - sptr[l])
               + smp[4] * (1.f - spbw[l]);
    float add = spfw[l] * smp[1] * a_find[n]
              + sptr[l] * (smp[2] * a_trans[n] + smp[3] * a_in[n] * a_find[n])
              + spbw[l] * smp[4] * a_w4[n];
    att_stack[(b * NN + n) * LL + l] = keep * st + add;
  }
  if (tid < LL) {
    int l = tid;
    stack_ptr[b * LL + l] = (smp[0] + smp[2] + smp[3]) * sptr[l] + smp[1] * spfw[l]
                          + (smp[4] + smp[5]) * spbw[l];
  }
}

// ---------------- host ----------------
static inline void launch_gemm(hipStream_t s, bool transw, int cb, int SK, const GemmP& g) {
  dim3 grid(cb, SK);
  if (transw) hipLaunchKernelGGL((gemm_part<true>), grid, dim3(256), 0, s, g);
  else        hipLaunchKernelGGL((gemm_part<false>), grid, dim3(256), 0, s, g);
}

extern "C" void kernel_launch(void* const* d_in, const int* in_sizes, int n_in,
                              void* d_out, int out_size, void* d_ws, size_t ws_size,
                              hipStream_t stream) {
  const int*   questions = (const int*)d_in[0];
  const int*   qlen      = (const int*)d_in[1];
  const float* conn      = (const float*)d_in[2];
  const int*   cat_mat   = (const int*)d_in[3];
  const int*   v_idx     = (const int*)d_in[4];
  const float* attr_emb  = (const float*)d_in[5];
  const float* edge_cat  = (const float*)d_in[6];
  const float* enc_emb   = (const float*)d_in[7];
  const float* Wx        = (const float*)d_in[8];
  const float* Wh        = (const float*)d_in[9];
  const float* b_lstm    = (const float*)d_in[10];
  const float* W_cq      = (const float*)d_in[11];
  const float* b_cq      = (const float*)d_in[12];
  const float* W_mod     = (const float*)d_in[13];
  const float* W_att     = (const float*)d_in[14];
  const float* W_q       = (const float*)d_in[15];
  const float* b_q       = (const float*)d_in[16];
  const float* W_find    = (const float*)d_in[17];
  const float* W_desc    = (const float*)d_in[18];
  const float* W_cls1    = (const float*)d_in[19];
  const float* b_cls1    = (const float*)d_in[20];
  const float* W_cls2    = (const float*)d_in[21];
  const float* b_cls2    = (const float*)d_in[22];
  float* logits = (float*)d_out;

  float* w = (float*)d_ws;
  size_t off = 0;
  float* outs      = w + off; off += (size_t)S * B * DH;      // 2,097,152
  float* embq      = w + off; off += (size_t)S * B * 320;     //   655,360
  float* part      = w + off; off += (size_t)2 * 1024 * 1024; // 2,097,152 (split-K partials)
  float* cq        = w + off; off += B * DH;
  float* am_buf    = w + off; off += B * 1032;
  float* c_ctrl    = w + off; off += B * DH;
  float* q_hidden  = w + off; off += B * DH;
  float* c_lstm    = w + off; off += B * DH;
  float* ci_buf    = w + off; off += B * DV;
  float* uwe_buf   = w + off; off += B * 528;
  float* att_stack = w + off; off += B * NN * LL;
  float* sptr_buf  = w + off; off += B * LL;
  float* mem       = w + off; off += B * DV;
  float* pooled    = w + off; off += B * DV;
  float* mp_buf    = w + off; off += B * MM;
  float* h1        = w + off; off += B * CLS;

  init_kernel<<<256, 256, 0, stream>>>(c_lstm, c_ctrl, att_stack, mem, sptr_buf);
  embq_kernel<<<S * B, 320, 0, stream>>>(questions, enc_emb, embq);

  // ---- LSTM: per step, split-K GEMM over [embq_t | h_{t-1}] @ [Wx;Wh] then gate epilogue ----
  for (int t = 0; t < S; ++t) {
    GemmP g;
    g.A0 = embq + (size_t)t * B * 320; g.A1 = (t == 0) ? nullptr : outs + (size_t)(t - 1) * B * DH;
    g.AK0 = 320;
    g.W0 = Wx; g.ld0 = 4 * DH; g.W0b = nullptr; g.ld0b = 0; g.Ca = 4 * DH;
    g.W1 = Wh; g.ld1 = 4 * DH; g.WK0 = 320; g.Kw0 = DW;
    g.out = part; g.C = 4 * DH; g.Cld = 4 * DH;
    int SK;
    if (t == 0) { g.K = 320; g.Kc = 160; SK = 2; }
    else        { g.K = 1344; g.Kc = 192; SK = 7; }
    launch_gemm(stream, false, 64, SK, g);
    lstm_gate_kernel<<<(B * DH) / 256, 256, 0, stream>>>(part, SK, b_lstm,
                                                         outs + (size_t)t * B * DH, c_lstm);
  }
  qhid_gather_kernel<<<B, 256, 0, stream>>>(outs, qlen, q_hidden);

  for (int it = 0; it < T_CTRL; ++it) {
    // cq = tanh([c_ctrl | q_hidden] @ W_cq + b_cq)   K=2048, C=1024
    {
      GemmP g = {c_ctrl, q_hidden, DH, W_cq, DH, nullptr, 0, DH, nullptr, 0, 2 * DH, 2 * DH,
                 part, DH, DH, 2 * DH, 256};
      launch_gemm(stream, false, 16, 8, g);
      reduce_k<2, 0><<<(64 * DH / 4 + 255) / 256, 256, 0, stream>>>(part, 8, DH, 64 * DH / 4, b_cq, cq, nullptr);
    }
    // [attW | mod_logits] = cq @ [W_att | W_mod]   K=1024, C=1030 (Cld=1032)
    {
      GemmP g = {cq, nullptr, DH, W_att, DH, W_mod, MM, DH, nullptr, 0, DH, DH,
                 part, DH + MM, 1032, DH, 128};
      launch_gemm(stream, false, 17, 8, g);
      reduce_k<0, 0><<<(64 * 1032 / 4 + 255) / 256, 256, 0, stream>>>(part, 8, 1032, 64 * 1032 / 4, nullptr, am_buf, nullptr);
    }
    attention_kernel<<<B, 256, 0, stream>>>(outs, am_buf, 1032, qlen, c_ctrl);
    // c_i = relu(c_ctrl @ W_q + b_q)   K=1024, C=512
    {
      GemmP g = {c_ctrl, nullptr, DH, W_q, DV, nullptr, 0, DV, nullptr, 0, DH, DH,
                 part, DV, DV, DH, 128};
      launch_gemm(stream, false, 8, 8, g);
      reduce_k<1, 0><<<(64 * DV / 4 + 255) / 256, 256, 0, stream>>>(part, 8, DV, 64 * DV / 4, b_q, ci_buf, nullptr);
    }
    // [u | we_logits] = c_i @ [W_find^T | edge^T]   K=512, C=528 (TRANSW)
    {
      GemmP g = {ci_buf, nullptr, DV, W_find, DV, edge_cat, DV, DV, nullptr, 0, DV, DV,
                 part, DV + NE, 528, DV, 64};
      launch_gemm(stream, true, 9, 8, g);
      reduce_k<0, 0><<<(64 * 528 / 4 + 255) / 256, 256, 0, stream>>>(part, 8, 528, 64 * 528 / 4, nullptr, uwe_buf, nullptr);
    }
    stack_kernel<<<B, 256, 0, stream>>>(v_idx, attr_emb, uwe_buf, am_buf, cat_mat, conn,
                                        sptr_buf, att_stack, sptr_buf, mp_buf, pooled);
    // mem = s04*mem + mp5*(pooled @ W_desc)   K=512, C=512
    {
      GemmP g = {pooled, nullptr, DV, W_desc, DV, nullptr, 0, DV, nullptr, 0, DV, DV,
                 part, DV, DV, DV, 64};
      launch_gemm(stream, false, 8, 8, g);
      reduce_k<0, 1><<<(64 * DV / 4 + 255) / 256, 256, 0, stream>>>(part, 8, DV, 64 * DV / 4, nullptr, mem, mp_buf);
    }
  }

  // classifier: h1 = relu([mem | q_hidden] @ W_cls1 + b_cls1)   K=1536, C=1024
  {
    GemmP g = {mem, q_hidden, DV, W_cls1, CLS, nullptr, 0, CLS, nullptr, 0, DV + DH, DV + DH,
               part, CLS, CLS, DV + DH, 192};
    launch_gemm(stream, false, 16, 8, g);
    reduce_k<1, 0><<<(64 * CLS / 4 + 255) / 256, 256, 0, stream>>>(part, 8, CLS, 64 * CLS / 4, b_cls1, h1, nullptr);
  }
  // logits = h1 @ W_cls2 + b_cls2   K=1024, C=28
  {
    GemmP g = {h1, nullptr, CLS, W_cls2, NA, nullptr, 0, NA, nullptr, 0, CLS, CLS,
               part, NA, NA, CLS, 256};
    launch_gemm(stream, false, 1, 4, g);
    reduce_k<0, 0><<<(64 * NA / 4 + 255) / 256, 256, 0, stream>>>(part, 4, NA, 64 * NA / 4, b_cls2, logits, nullptr);
  }
}

// Round 3
// 2480.972 us; speedup vs baseline: 2.4942x; 1.2885x over previous
//
#include <hip/hip_runtime.h>
#include <math.h>

#define B 64
#define S 32
#define NN 128
#define DV 512
#define DW 300
#define DH 1024
#define CLS 1024
#define T_CTRL 12
#define LL 4
#define NA 28
#define NE 16
#define MM 6

__device__ __forceinline__ float sigmoidf_(float x) { return 1.0f / (1.0f + expf(-x)); }

// ---------------- init state ----------------
__global__ void init_kernel(float* c_lstm, float* c_ctrl, float* att_stack, float* mem, float* stack_ptr) {
  int idx = blockIdx.x * 256 + threadIdx.x;
  if (idx < B * DH) { c_lstm[idx] = 0.f; c_ctrl[idx] = 0.f; }
  if (idx < B * NN * LL) att_stack[idx] = 0.f;
  if (idx < B * DV) mem[idx] = 0.f;
  if (idx < B * LL) stack_ptr[idx] = ((idx & (LL - 1)) == 0) ? 1.f : 0.f;
}

// ---------------- embq: gathered question embeddings, rows t*B+b, padded K 300->320 ----------------
__global__ void embq_kernel(const int* __restrict__ questions, const float* __restrict__ enc_emb,
                            float* __restrict__ embq) {
  int row = blockIdx.x;
  int t = row >> 6, b = row & 63;
  int qid = questions[b * S + t];
  int c = threadIdx.x;
  embq[(size_t)row * 320 + c] = (c < DW) ? enc_emb[(size_t)qid * DW + c] : 0.f;
}

// ---------------- split-K partial GEMM (unchanged from round 2) ----------------
struct GemmP {
  const float* A0; const float* A1; int AK0;
  const float* W0; int ld0;
  const float* W0b; int ld0b; int Ca;
  const float* W1; int ld1; int WK0; int Kw0;
  float* out; int C; int Cld; int K; int Kc;
};

template<bool TRANSW>
__global__ __launch_bounds__(256) void gemm_part(GemmP g) {
  __shared__ float Ast[32][65];
  __shared__ float Ws[32][64];
  const int tid = threadIdx.x;
  const int j0 = blockIdx.x * 64;
  const int kbeg = blockIdx.y * g.Kc;
  const int kend = (kbeg + g.Kc < g.K) ? kbeg + g.Kc : g.K;
  const int rg = tid & 15, cg = tid >> 4;
  float acc[4][4] = {};

  for (int kt = kbeg; kt < kend; kt += 32) {
    #pragma unroll
    for (int it = 0; it < 2; ++it) {
      int idx = tid + it * 256;
      int r = idx >> 3, k4 = (idx & 7) * 4;
      int k = kt + k4;
      float4 av;
      if (k < g.AK0) av = *(const float4*)&g.A0[(size_t)r * g.AK0 + k];
      else           av = *(const float4*)&g.A1[(size_t)r * (g.K - g.AK0) + (k - g.AK0)];
      Ast[k4 + 0][r] = av.x; Ast[k4 + 1][r] = av.y; Ast[k4 + 2][r] = av.z; Ast[k4 + 3][r] = av.w;
    }
    if (!TRANSW) {
      #pragma unroll
      for (int it = 0; it < 2; ++it) {
        int idx = tid + it * 256;
        int kk = kt + (idx >> 4);
        int j4 = (idx & 15) * 4;
        const float* wrow = nullptr;
        if (kk < g.WK0) { if (kk < g.Kw0) wrow = g.W0 + (size_t)kk * g.ld0; }
        else { wrow = g.W1 + (size_t)(kk - g.WK0) * g.ld1; }
        float v[4];
        #pragma unroll
        for (int m = 0; m < 4; ++m) {
          int j = j0 + j4 + m;
          float x = 0.f;
          if (j < g.C) {
            if (j < g.Ca) { if (wrow) x = wrow[j]; }
            else { if (kk < g.Kw0) x = g.W0b[(size_t)kk * g.ld0b + (j - g.Ca)]; }
          }
          v[m] = x;
        }
        *(float4*)&Ws[idx >> 4][j4] = make_float4(v[0], v[1], v[2], v[3]);
      }
    } else {
      #pragma unroll
      for (int it = 0; it < 2; ++it) {
        int idx = tid + it * 256;
        int jloc = idx >> 3, k4 = (idx & 7) * 4;
        int j = j0 + jloc;
        float4 wv = make_float4(0.f, 0.f, 0.f, 0.f);
        if (j < g.C) {
          const float* wr = (j < g.Ca) ? g.W0 + (size_t)j * g.ld0
                                       : g.W0b + (size_t)(j - g.Ca) * g.ld0b;
          wv = *(const float4*)&wr[kt + k4];
        }
        Ws[k4 + 0][jloc] = wv.x; Ws[k4 + 1][jloc] = wv.y; Ws[k4 + 2][jloc] = wv.z; Ws[k4 + 3][jloc] = wv.w;
      }
    }
    __syncthreads();
    #pragma unroll
    for (int k = 0; k < 32; ++k) {
      float a0 = Ast[k][rg], a1 = Ast[k][rg + 16], a2 = Ast[k][rg + 32], a3 = Ast[k][rg + 48];
      float4 w = *(const float4*)&Ws[k][cg * 4];
      acc[0][0] = fmaf(a0, w.x, acc[0][0]); acc[0][1] = fmaf(a0, w.y, acc[0][1]);
      acc[0][2] = fmaf(a0, w.z, acc[0][2]); acc[0][3] = fmaf(a0, w.w, acc[0][3]);
      acc[1][0] = fmaf(a1, w.x, acc[1][0]); acc[1][1] = fmaf(a1, w.y, acc[1][1]);
      acc[1][2] = fmaf(a1, w.z, acc[1][2]); acc[1][3] = fmaf(a1, w.w, acc[1][3]);
      acc[2][0] = fmaf(a2, w.x, acc[2][0]); acc[2][1] = fmaf(a2, w.y, acc[2][1]);
      acc[2][2] = fmaf(a2, w.z, acc[2][2]); acc[2][3] = fmaf(a2, w.w, acc[2][3]);
      acc[3][0] = fmaf(a3, w.x, acc[3][0]); acc[3][1] = fmaf(a3, w.y, acc[3][1]);
      acc[3][2] = fmaf(a3, w.z, acc[3][2]); acc[3][3] = fmaf(a3, w.w, acc[3][3]);
    }
    __syncthreads();
  }
  float* op = g.out + (size_t)blockIdx.y * 64 * g.Cld;
  int j = j0 + cg * 4;
  if (j < g.Cld) {
    #pragma unroll
    for (int m = 0; m < 4; ++m)
      *(float4*)&op[(size_t)(rg + 16 * m) * g.Cld + j] = make_float4(acc[m][0], acc[m][1], acc[m][2], acc[m][3]);
  }
}

// ---------------- split-K reduce + epilogue ----------------
template<int ACT, int EPI>
__global__ __launch_bounds__(256) void reduce_k(const float* __restrict__ part, int SK, int Cld, int total4,
                                                const float* __restrict__ bias, float* __restrict__ out,
                                                const float* __restrict__ mp) {
  int idx = blockIdx.x * 256 + threadIdx.x;
  if (idx >= total4) return;
  size_t stride4 = (size_t)16 * Cld;
  const float4* p4 = (const float4*)part;
  float4 s = p4[idx];
  for (int k = 1; k < SK; ++k) {
    float4 p = p4[(size_t)k * stride4 + idx];
    s.x += p.x; s.y += p.y; s.z += p.z; s.w += p.w;
  }
  if (EPI == 1) {
    int r = idx / (Cld / 4);
    const float* m = mp + r * MM;
    float s04 = m[0] + m[1] + m[2] + m[3] + m[4];
    float4 o = ((float4*)out)[idx];
    s.x = s04 * o.x + m[5] * s.x; s.y = s04 * o.y + m[5] * s.y;
    s.z = s04 * o.z + m[5] * s.z; s.w = s04 * o.w + m[5] * s.w;
  } else {
    if (bias) {
      int j = (idx * 4) % Cld;
      float4 bb = *(const float4*)&bias[j];
      s.x += bb.x; s.y += bb.y; s.z += bb.z; s.w += bb.w;
    }
    if (ACT == 1) { s.x = fmaxf(s.x, 0.f); s.y = fmaxf(s.y, 0.f); s.z = fmaxf(s.z, 0.f); s.w = fmaxf(s.w, 0.f); }
    else if (ACT == 2) { s.x = tanhf(s.x); s.y = tanhf(s.y); s.z = tanhf(s.z); s.w = tanhf(s.w); }
  }
  ((float4*)out)[idx] = s;
}

// ---------------- LSTM gate epilogue ----------------
__global__ __launch_bounds__(256) void lstm_gate_kernel(const float* __restrict__ part, int SK,
                                                        const float* __restrict__ b_lstm,
                                                        float* __restrict__ h_out, float* __restrict__ c_st) {
  int idx = blockIdx.x * 256 + threadIdx.x;
  int b = idx >> 10, j = idx & 1023;
  const float* pb = part + (size_t)b * 4096;
  float gi = 0.f, gf = 0.f, gg = 0.f, go = 0.f;
  for (int k = 0; k < SK; ++k) {
    const float* p = pb + (size_t)k * 64 * 4096;
    gi += p[j]; gf += p[1024 + j]; gg += p[2048 + j]; go += p[3072 + j];
  }
  gi += b_lstm[j]; gf += b_lstm[1024 + j]; gg += b_lstm[2048 + j]; go += b_lstm[3072 + j];
  float c = sigmoidf_(gf) * c_st[idx] + sigmoidf_(gi) * tanhf(gg);
  h_out[idx] = sigmoidf_(go) * tanhf(c);
  c_st[idx] = c;
}

// ---------------- q_hidden gather ----------------
__global__ void qhid_gather_kernel(const float* __restrict__ outs, const int* __restrict__ qlen,
                                   float* __restrict__ q_hidden) {
  int b = blockIdx.x;
  int t = qlen[b] - 1;
  for (int k = threadIdx.x; k < DH; k += 256)
    q_hidden[b * DH + k] = outs[((size_t)t * B + b) * DH + k];
}

// ---------------- attention, split wide ----------------
// al[s][b] = dot(outs[s,b,:], attW[b,:]); one wave per (s,b); grid 512 x 256
__global__ __launch_bounds__(256) void al_kernel(const float* __restrict__ outs,
                                                 const float* __restrict__ am,
                                                 float* __restrict__ al) {
  int idx = blockIdx.x * 4 + (threadIdx.x >> 6);   // 0..2047
  int s = idx >> 6, b = idx & 63, lane = threadIdx.x & 63;
  const float4* orow = (const float4*)&outs[((size_t)s * B + b) * DH];
  const float4* aw = (const float4*)&am[(size_t)b * 1032];
  float p = 0.f;
  #pragma unroll
  for (int q = 0; q < 4; ++q) {
    float4 f = orow[lane + 64 * q], w = aw[lane + 64 * q];
    p += f.x * w.x + f.y * w.y + f.z * w.z + f.w * w.w;
  }
  #pragma unroll
  for (int off = 32; off > 0; off >>= 1) p += __shfl_xor(p, off);
  if (lane == 0) al[s * B + b] = p;
}

// c_ctrl[b,h] = sum_s softmax(al)[s,b] * outs[s,b,h]; grid 256 (b = bid>>2, 256 h each)
__global__ __launch_bounds__(256) void cctrl_kernel(const float* __restrict__ outs,
                                                    const float* __restrict__ al,
                                                    const int* __restrict__ qlen,
                                                    float* __restrict__ c_ctrl) {
  int bid = blockIdx.x, tid = threadIdx.x;
  int b = bid >> 2, h = (bid & 3) * 256 + tid;
  __shared__ float cvs[S];
  if (tid < 64) {
    int len = qlen[b];
    float v = (tid < S && tid < len) ? al[tid * B + b] : -1e9f;
    float mx = v;
    #pragma unroll
    for (int off = 32; off > 0; off >>= 1) mx = fmaxf(mx, __shfl_xor(mx, off));
    float e = (tid < S && tid < len) ? expf(v - mx) : 0.f;
    float sm = e;
    #pragma unroll
    for (int off = 32; off > 0; off >>= 1) sm += __shfl_xor(sm, off);
    if (tid < S) cvs[tid] = e / sm;
  }
  __syncthreads();
  float acc = 0.f;
  #pragma unroll 8
  for (int s = 0; s < S; ++s)
    acc = fmaf(cvs[s], outs[((size_t)s * B + b) * DH + h], acc);
  c_ctrl[b * DH + h] = acc;
}

// ---------------- stack machine, split wide ----------------
// prep: per-b softmaxes (we, module), validity/smp, pointer shifts, a_in/a_w4/asum. grid 64 x 64
__global__ __launch_bounds__(64) void prep_kernel(
    const float* __restrict__ uwe, const float* __restrict__ am,
    const float* __restrict__ stack_ptr_in, const float* __restrict__ att_stack,
    float* __restrict__ we_out, float* __restrict__ mp_out, float* __restrict__ spv,
    float* __restrict__ a_in_buf, float* __restrict__ a_w4_buf, float* __restrict__ asum_buf)
{
  int b = blockIdx.x, lane = threadIdx.x;
  __shared__ float sp[12];
  if (lane == 0) {
    const float* wl = &uwe[(size_t)b * 528 + 512];
    float mx = wl[0];
    for (int e = 1; e < NE; ++e) mx = fmaxf(mx, wl[e]);
    float ex[NE], sm = 0.f;
    for (int e = 0; e < NE; ++e) { ex[e] = expf(wl[e] - mx); sm += ex[e]; }
    for (int e = 0; e < NE; ++e) we_out[b * NE + e] = ex[e] / sm;
    const float* ml = &am[(size_t)b * 1032 + 1024];
    float mx2 = ml[0];
    for (int m = 1; m < MM; ++m) mx2 = fmaxf(mx2, ml[m]);
    float e6[MM], sm2 = 0.f;
    for (int m = 0; m < MM; ++m) { e6[m] = expf(ml[m] - mx2); sm2 += e6[m]; }
    float p0 = stack_ptr_in[b * LL + 0], p1 = stack_ptr_in[b * LL + 1];
    float p2 = stack_ptr_in[b * LL + 2], p3 = stack_ptr_in[b * LL + 3];
    sp[0] = p0; sp[1] = p1; sp[2] = p2; sp[3] = p3;
    sp[4] = 0.f;     sp[5] = p0; sp[6] = p1; sp[7] = p2 + p3;
    sp[8] = p0 + p1; sp[9] = p2; sp[10] = p3; sp[11] = 0.f;
    for (int i = 0; i < 12; ++i) spv[b * 12 + i] = sp[i];
    float val[MM];
    val[0] = rintf(p0 + p1 + p2 + p3);
    val[1] = rintf(p0 + p1 + p2);
    val[2] = rintf(p1 + p2 + p3);
    val[3] = val[2];
    val[4] = rintf(p2 + p3);
    val[5] = val[2];
    float mpv[MM], ssum = 0.f;
    #pragma unroll
    for (int m = 0; m < MM; ++m) { mpv[m] = (e6[m] / sm2) * val[m]; ssum += mpv[m]; }
    float inv = (ssum > 0.f) ? 1.f / ssum : 1.f;
    #pragma unroll
    for (int m = 0; m < MM; ++m) mp_out[b * MM + m] = mpv[m] * inv;
  }
  __syncthreads();
  float s2 = 0.f;
  #pragma unroll
  for (int i = 0; i < 2; ++i) {
    int n = lane + 64 * i;
    float4 st = *(const float4*)&att_stack[(b * NN + n) * LL];
    float ain = st.x * sp[0] + st.y * sp[1] + st.z * sp[2] + st.w * sp[3];
    float ap  = st.x * sp[8] + st.y * sp[9] + st.z * sp[10] + st.w * sp[11];
    a_in_buf[b * NN + n] = ain;
    a_w4_buf[b * NN + n] = fminf(ap, ain);
    s2 += ain;
  }
  #pragma unroll
  for (int off = 32; off > 0; off >>= 1) s2 += __shfl_xor(s2, off);
  if (lane == 0) asum_buf[b] = s2 + 1e-6f;
}

// a_find[b][n] = sigmoid(dot(attr_emb[vid], u)/sqrt(DV)); one wave per (b,n); grid 2048 x 256
__global__ __launch_bounds__(256) void afind_kernel(
    const int* __restrict__ v_idx, const float* __restrict__ attr_emb,
    const float* __restrict__ uwe, float* __restrict__ a_find)
{
  int idx = blockIdx.x * 4 + (threadIdx.x >> 6);   // 0..8191
  int b = idx >> 7, n = idx & 127, lane = threadIdx.x & 63;
  const float4* fp = (const float4*)&attr_emb[(size_t)v_idx[b * NN + n] * DV];
  const float4* up = (const float4*)&uwe[(size_t)b * 528];
  float p = 0.f;
  #pragma unroll
  for (int q = 0; q < 2; ++q) {
    float4 f = fp[lane + 64 * q], u = up[lane + 64 * q];
    p += f.x * u.x + f.y * u.y + f.z * u.z + f.w * u.w;
  }
  #pragma unroll
  for (int off = 32; off > 0; off >>= 1) p += __shfl_xor(p, off);
  if (lane == 0) a_find[b * NN + n] = sigmoidf_(p * 0.04419417382415922f);
}

// a_trans[b][i] = min(sum_j we[cat]*conn*a_in, 1); one wave per (b,i); grid 2048 x 256
__global__ __launch_bounds__(256) void atrans_kernel(
    const int* __restrict__ cat_mat, const float* __restrict__ conn,
    const float* __restrict__ we, const float* __restrict__ a_in,
    float* __restrict__ a_trans)
{
  int b = blockIdx.x >> 5, ig = blockIdx.x & 31;
  int tid = threadIdx.x, lane = tid & 63;
  __shared__ float ain[NN];
  __shared__ float wes[NE];
  if (tid < NN) ain[tid] = a_in[b * NN + tid];
  else if (tid < NN + NE) wes[tid - NN] = we[b * NE + tid - NN];
  __syncthreads();
  int i = ig * 4 + (tid >> 6);
  const int* crow = &cat_mat[((size_t)b * NN + i) * NN];
  const float* nrow = &conn[((size_t)b * NN + i) * NN];
  float acc = 0.f;
  #pragma unroll
  for (int q = 0; q < 2; ++q) {
    int j = lane + 64 * q;
    acc = fmaf(wes[crow[j]] * nrow[j], ain[j], acc);
  }
  #pragma unroll
  for (int off = 32; off > 0; off >>= 1) acc += __shfl_xor(acc, off);
  if (lane == 0) a_trans[b * NN + i] = fminf(acc, 1.f);
}

// pooled[b][d] = sum_n a_in[n]*attr_emb[vid[n],d] / asum; grid 128 x 256
__global__ __launch_bounds__(256) void pooled_kernel(
    const int* __restrict__ v_idx, const float* __restrict__ attr_emb,
    const float* __restrict__ a_in, const float* __restrict__ asum,
    float* __restrict__ pooled)
{
  int b = blockIdx.x >> 1, d = (blockIdx.x & 1) * 256 + threadIdx.x;
  int tid = threadIdx.x;
  __shared__ float ain[NN];
  __shared__ int vid[NN];
  if (tid < NN) { ain[tid] = a_in[b * NN + tid]; vid[tid] = v_idx[b * NN + tid]; }
  __syncthreads();
  float acc = 0.f;
  #pragma unroll 4
  for (int n = 0; n < NN; ++n)
    acc = fmaf(ain[n], attr_emb[(size_t)vid[n] * DV + d], acc);
  pooled[b * DV + d] = acc / asum[b];
}

// att_stack + stack_ptr update; grid 64 x 256
__global__ __launch_bounds__(256) void update_kernel(
    const float* __restrict__ spv, const float* __restrict__ mp,
    const float* __restrict__ a_find, const float* __restrict__ a_in,
    const float* __restrict__ a_trans, const float* __restrict__ a_w4,
    float* __restrict__ att_stack, float* __restrict__ stack_ptr)
{
  int b = blockIdx.x, tid = threadIdx.x;
  __shared__ float sp[12], smp[MM];
  if (tid < 12) sp[tid] = spv[b * 12 + tid];
  else if (tid < 12 + MM) smp[tid - 12] = mp[b * MM + (tid - 12)];
  __syncthreads();
  #pragma unroll
  for (int i = 0; i < 2; ++i) {
    int e = tid + i * 256;
    int n = e >> 2, l = e & 3;
    float st = att_stack[(b * NN + n) * LL + l];
    float keep = smp[0] + smp[5] + smp[1] * (1.f - sp[4 + l]) + (smp[2] + smp[3]) * (1.f - sp[l])
               + smp[4] * (1.f - sp[8 + l]);
    float add = sp[4 + l] * smp[1] * a_find[b * NN + n]
              + sp[l] * (smp[2] * a_trans[b * NN + n] + smp[3] * a_in[b * NN + n] * a_find[b * NN + n])
              + sp[8 + l] * smp[4] * a_w4[b * NN + n];
    att_stack[(b * NN + n) * LL + l] = keep * st + add;
  }
  if (tid < LL)
    stack_ptr[b * LL + tid] = (smp[0] + smp[2] + smp[3]) * sp[tid] + smp[1] * sp[4 + tid]
                            + (smp[4] + smp[5]) * sp[8 + tid];
}

// ---------------- host ----------------
static inline void launch_gemm(hipStream_t s, bool transw, int cb, int SK, const GemmP& g) {
  dim3 grid(cb, SK);
  if (transw) hipLaunchKernelGGL((gemm_part<true>), grid, dim3(256), 0, s, g);
  else        hipLaunchKernelGGL((gemm_part<false>), grid, dim3(256), 0, s, g);
}

extern "C" void kernel_launch(void* const* d_in, const int* in_sizes, int n_in,
                              void* d_out, int out_size, void* d_ws, size_t ws_size,
                              hipStream_t stream) {
  const int*   questions = (const int*)d_in[0];
  const int*   qlen      = (const int*)d_in[1];
  const float* conn      = (const float*)d_in[2];
  const int*   cat_mat   = (const int*)d_in[3];
  const int*   v_idx     = (const int*)d_in[4];
  const float* attr_emb  = (const float*)d_in[5];
  const float* edge_cat  = (const float*)d_in[6];
  const float* enc_emb   = (const float*)d_in[7];
  const float* Wx        = (const float*)d_in[8];
  const float* Wh        = (const float*)d_in[9];
  const float* b_lstm    = (const float*)d_in[10];
  const float* W_cq      = (const float*)d_in[11];
  const float* b_cq      = (const float*)d_in[12];
  const float* W_mod     = (const float*)d_in[13];
  const float* W_att     = (const float*)d_in[14];
  const float* W_q       = (const float*)d_in[15];
  const float* b_q       = (const float*)d_in[16];
  const float* W_find    = (const float*)d_in[17];
  const float* W_desc    = (const float*)d_in[18];
  const float* W_cls1    = (const float*)d_in[19];
  const float* b_cls1    = (const float*)d_in[20];
  const float* W_cls2    = (const float*)d_in[21];
  const float* b_cls2    = (const float*)d_in[22];
  float* logits = (float*)d_out;

  float* w = (float*)d_ws;
  size_t off = 0;
  float* outs      = w + off; off += (size_t)S * B * DH;
  float* embq      = w + off; off += (size_t)S * B * 320;
  float* part      = w + off; off += (size_t)2 * 1024 * 1024;
  float* cq        = w + off; off += B * DH;
  float* am_buf    = w + off; off += B * 1032;
  float* c_ctrl    = w + off; off += B * DH;
  float* q_hidden  = w + off; off += B * DH;
  float* c_lstm    = w + off; off += B * DH;
  float* ci_buf    = w + off; off += B * DV;
  float* uwe_buf   = w + off; off += B * 528;
  float* att_stack = w + off; off += B * NN * LL;
  float* sptr_buf  = w + off; off += B * LL;
  float* mem       = w + off; off += B * DV;
  float* pooled    = w + off; off += B * DV;
  float* mp_buf    = w + off; off += B * MM;
  float* h1        = w + off; off += B * CLS;
  float* al_buf    = w + off; off += S * B;
  float* we_buf    = w + off; off += B * NE;
  float* spv_buf   = w + off; off += B * 12;
  float* afind_buf = w + off; off += B * NN;
  float* ain_buf   = w + off; off += B * NN;
  float* aw4_buf   = w + off; off += B * NN;
  float* atr_buf   = w + off; off += B * NN;
  float* asum_buf  = w + off; off += B;

  init_kernel<<<256, 256, 0, stream>>>(c_lstm, c_ctrl, att_stack, mem, sptr_buf);
  embq_kernel<<<S * B, 320, 0, stream>>>(questions, enc_emb, embq);

  for (int t = 0; t < S; ++t) {
    GemmP g;
    g.A0 = embq + (size_t)t * B * 320; g.A1 = (t == 0) ? nullptr : outs + (size_t)(t - 1) * B * DH;
    g.AK0 = 320;
    g.W0 = Wx; g.ld0 = 4 * DH; g.W0b = nullptr; g.ld0b = 0; g.Ca = 4 * DH;
    g.W1 = Wh; g.ld1 = 4 * DH; g.WK0 = 320; g.Kw0 = DW;
    g.out = part; g.C = 4 * DH; g.Cld = 4 * DH;
    int SK;
    if (t == 0) { g.K = 320; g.Kc = 160; SK = 2; }
    else        { g.K = 1344; g.Kc = 192; SK = 7; }
    launch_gemm(stream, false, 64, SK, g);
    lstm_gate_kernel<<<(B * DH) / 256, 256, 0, stream>>>(part, SK, b_lstm,
                                                         outs + (size_t)t * B * DH, c_lstm);
  }
  qhid_gather_kernel<<<B, 256, 0, stream>>>(outs, qlen, q_hidden);

  for (int it = 0; it < T_CTRL; ++it) {
    // cq = tanh([c_ctrl | q_hidden] @ W_cq + b_cq)
    {
      GemmP g = {c_ctrl, q_hidden, DH, W_cq, DH, nullptr, 0, DH, nullptr, 0, 2 * DH, 2 * DH,
                 part, DH, DH, 2 * DH, 256};
      launch_gemm(stream, false, 16, 8, g);
      reduce_k<2, 0><<<(64 * DH / 4 + 255) / 256, 256, 0, stream>>>(part, 8, DH, 64 * DH / 4, b_cq, cq, nullptr);
    }
    // [attW | mod_logits] = cq @ [W_att | W_mod]
    {
      GemmP g = {cq, nullptr, DH, W_att, DH, W_mod, MM, DH, nullptr, 0, DH, DH,
                 part, DH + MM, 1032, DH, 128};
      launch_gemm(stream, false, 17, 8, g);
      reduce_k<0, 0><<<(64 * 1032 / 4 + 255) / 256, 256, 0, stream>>>(part, 8, 1032, 64 * 1032 / 4, nullptr, am_buf, nullptr);
    }
    al_kernel<<<512, 256, 0, stream>>>(outs, am_buf, al_buf);
    cctrl_kernel<<<256, 256, 0, stream>>>(outs, al_buf, qlen, c_ctrl);
    // c_i = relu(c_ctrl @ W_q + b_q)
    {
      GemmP g = {c_ctrl, nullptr, DH, W_q, DV, nullptr, 0, DV, nullptr, 0, DH, DH,
                 part, DV, DV, DH, 128};
      launch_gemm(stream, false, 8, 8, g);
      reduce_k<1, 0><<<(64 * DV / 4 + 255) / 256, 256, 0, stream>>>(part, 8, DV, 64 * DV / 4, b_q, ci_buf, nullptr);
    }
    // [u | we_logits] = c_i @ [W_find^T | edge^T]
    {
      GemmP g = {ci_buf, nullptr, DV, W_find, DV, edge_cat, DV, DV, nullptr, 0, DV, DV,
                 part, DV + NE, 528, DV, 64};
      launch_gemm(stream, true, 9, 8, g);
      reduce_k<0, 0><<<(64 * 528 / 4 + 255) / 256, 256, 0, stream>>>(part, 8, 528, 64 * 528 / 4, nullptr, uwe_buf, nullptr);
    }
    prep_kernel<<<64, 64, 0, stream>>>(uwe_buf, am_buf, sptr_buf, att_stack,
                                       we_buf, mp_buf, spv_buf, ain_buf, aw4_buf, asum_buf);
    afind_kernel<<<2048, 256, 0, stream>>>(v_idx, attr_emb, uwe_buf, afind_buf);
    atrans_kernel<<<2048, 256, 0, stream>>>(cat_mat, conn, we_buf, ain_buf, atr_buf);
    pooled_kernel<<<128, 256, 0, stream>>>(v_idx, attr_emb, ain_buf, asum_buf, pooled);
    update_kernel<<<64, 256, 0, stream>>>(spv_buf, mp_buf, afind_buf, ain_buf, atr_buf, aw4_buf,
                                          att_stack, sptr_buf);
    // mem = s04*mem + mp5*(pooled @ W_desc)
    {
      GemmP g = {pooled, nullptr, DV, W_desc, DV, nullptr, 0, DV, nullptr, 0, DV, DV,
                 part, DV, DV, DV, 64};
      launch_gemm(stream, false, 8, 8, g);
      reduce_k<0, 1><<<(64 * DV / 4 + 255) / 256, 256, 0, stream>>>(part, 8, DV, 64 * DV / 4, nullptr, mem, mp_buf);
    }
  }

  // classifier
  {
    GemmP g = {mem, q_hidden, DV, W_cls1, CLS, nullptr, 0, CLS, nullptr, 0, DV + DH, DV + DH,
               part, CLS, CLS, DV + DH, 192};
    launch_gemm(stream, false, 16, 8, g);
    reduce_k<1, 0><<<(64 * CLS / 4 + 255) / 256, 256, 0, stream>>>(part, 8, CLS, 64 * CLS / 4, b_cls1, h1, nullptr);
  }
  {
    GemmP g = {h1, nullptr, CLS, W_cls2, NA, nullptr, 0, NA, nullptr, 0, CLS, CLS,
               part, NA, NA, CLS, 256};
    launch_gemm(stream, false, 1, 4, g);
    reduce_k<0, 0><<<(64 * NA / 4 + 255) / 256, 256, 0, stream>>>(part, 4, NA, 64 * NA / 4, b_cls2, logits, nullptr);
  }
}